// Round 12
// baseline (71.029 us; speedup 1.0000x reference)
//
#include <hip/hip_runtime.h>
#include <math.h>

#define W 512
#define H 512
#define NUM_R 725
#define NUM_T 180
#define RCHUNK 32               // sweep-rows per block; grid (16,180) = 2880 blocks
#define NCHUNK (H / RCHUNK)     // 16
#define RPAD 768                // padded rho bins
#define NWAVE 2                 // waves per block (128 threads)

// Per-theta constants, computed once (bitwise-identical f64 path) in
// transpose_k's block (0,0) and consumed by every scatter block.
struct ThetaConst {
    double loop_co;     // du per sweep row (signed)
    double lane_co;     // du per pixel along lane axis (signed)
    long long laneq;    // rint(lane_co * 2^32)
    long long lqa;      // |rint(loop_co * 2^32)|
    unsigned hwq;       // (lane_a * 0.5 * 2^32)
    unsigned B;         // 2*hwq : hit iff lo32(u) <= B
    int P;              // run-batch length {16,8,4,2}
    int flags;          // bit0 = use_x, bit1 = neg(loop_co<0)
};                      // 48 bytes

// ws layout: imgT [W*H] ; partials [NCHUNK*NUM_T*RPAD] ; ThetaConst[NUM_T]
#define WS_CONST_FLOATS ((sizeof(ThetaConst) * NUM_T + 3) / 4)
#define WS_FLOATS ((size_t)W * H + (size_t)NCHUNK * NUM_T * RPAD + WS_CONST_FLOATS)

// ---------------------------------------------------------------------------
// R18 (kept): weight-ordered dispatch. Per-block cost rises with 256/P; P is
// monotone in distance-from-axis d = min(t%90, 90-t%90). Rank r (=blockIdx.y)
// -> theta, d descending: with all blocks co-resident this stratifies per-CU
// weight assignment (measured -2.0us, R18).
// ---------------------------------------------------------------------------
__device__ __forceinline__ int theta_of_rank(int r) {
    if (r == 0) return 45;
    if (r == 1) return 135;
    if (r == 178) return 0;
    if (r == 179) return 90;
    const int g = (r - 2) >> 2, j = (r - 2) & 3;
    const int d = 44 - g;                 // 44..1
    if (j == 0) return d;
    if (j == 1) return 90 - d;
    if (j == 2) return 90 + d;
    return 180 - d;
}

// ---------------------------------------------------------------------------
// Transpose 512x512 f32 + per-theta constant table (piggyback, block (0,0)).
// f64 expressions are IDENTICAL to the validated R13 in-kernel preamble, so
// scatter results are bitwise unchanged.
// ---------------------------------------------------------------------------
__global__ __launch_bounds__(256) void transpose_k(const float* __restrict__ in,
                                                   float* __restrict__ out,
                                                   ThetaConst* __restrict__ tc) {
    __shared__ float tile[32][33];
    const int bx = blockIdx.x * 32, by = blockIdx.y * 32;
    const int tx = threadIdx.x, ty = threadIdx.y;  // block (32, 8)
#pragma unroll
    for (int j = 0; j < 32; j += 8)
        tile[ty + j][tx] = in[(size_t)(by + ty + j) * W + (bx + tx)];
    __syncthreads();
#pragma unroll
    for (int j = 0; j < 32; j += 8)
        out[(size_t)(bx + ty + j) * H + (by + tx)] = tile[tx][ty + j];

    // ---- theta-constant table (one block; hidden under the other 255) ----
    if (bx == 0 && by == 0) {
        const int t = ty * 32 + tx;
        if (t < NUM_T) {
            const double theta = (double)t * (M_PI / 180.0);
            const double s = sin(theta);
            const double c = cos(theta);
            const bool use_x = fabs(s) >= fabs(c);
            const double diag = sqrt(524288.0);
            const double step = (2.0 * diag) / 724.0;
            const double inv_step = 1.0 / step;

            const double lane_co = (use_x ? s : c) * inv_step;
            const double loop_co = (use_x ? c : s) * inv_step;
            const double lane_a  = fabs(lane_co);
            const double loop_a  = fabs(loop_co);

            const double SC = 4294967296.0;  // 2^32
            ThetaConst k;
            k.loop_co = loop_co;
            k.lane_co = lane_co;
            k.laneq   = (long long)rint(lane_co * SC);
            k.lqa     = llabs((long long)rint(loop_co * SC));
            k.hwq     = (unsigned)(lane_a * 0.5 * SC);
            k.B       = 2u * k.hwq;
            int P = 2;
            if      (lane_a + 15.0 * loop_a < 0.98) P = 16;
            else if (lane_a +  7.0 * loop_a < 0.98) P = 8;
            else if (lane_a +  3.0 * loop_a < 0.98) P = 4;
            k.P     = P;
            k.flags = (use_x ? 1 : 0) | ((loop_co < 0.0) ? 2 : 0);
            tc[t] = k;
        }
    }
}

// ---------------------------------------------------------------------------
// Run-batched inner loop: 16 consecutive rows, flush every P rows.
// Invariant (guaranteed by P selection: lane_a + (P-1)*loop_a < 0.98):
// within a P-row window, all hits (frac(u) <= B) lie in ONE bin = hi32(u) at
// the window's last row. Zero-acc flushes land on a valid bin (harmless).
// Validated R13/R16 loop (R17's deep prefetch measured WORSE: 73.2).
// ---------------------------------------------------------------------------
template <int P>
__device__ __forceinline__ void run16(const float4* __restrict__ rp, int rstep,
                                      long long u, long long lqa,
                                      long long L1, long long L2, long long L3,
                                      unsigned B, float* __restrict__ racc_w) {
#pragma unroll
    for (int per = 0; per < 16 / P; ++per) {
        float a0 = 0.f, a1 = 0.f, a2 = 0.f, a3 = 0.f;
        long long u0 = 0, u1 = 0, u2 = 0, u3 = 0;
#pragma unroll
        for (int p = 0; p < P; ++p) {
            const float4 v = rp[(per * P + p) * rstep];
            u0 = u; u1 = u + L1; u2 = u + L2; u3 = u + L3;
            a0 += ((unsigned)u0 <= B) ? v.x : 0.f;
            a1 += ((unsigned)u1 <= B) ? v.y : 0.f;
            a2 += ((unsigned)u2 <= B) ? v.z : 0.f;
            a3 += ((unsigned)u3 <= B) ? v.w : 0.f;
            if (p < P - 1) u += lqa;
        }
        // one RMW pair per slot per P rows (same-thread in-order; lane bins
        // distinct: slot spacing 4*lane_a >= 1.38 bins; wave-private racc)
        racc_w[(int)(u0 >> 32)] += a0;
        racc_w[(int)(u1 >> 32)] += a1;
        racc_w[(int)(u2 >> 32)] += a2;
        racc_w[(int)(u3 >> 32)] += a3;
        u += lqa;
    }
}

// ---------------------------------------------------------------------------
// Scatter Hough — R19: 128-thread / 32-row blocks (2880 blocks, 2 waves,
// 6 KB racc). Per-thread work identical to R18 (32 rows x 4 cols, same u
// math); finer granules double per-CU strata (5.6 -> 11.25 blocks/CU, all
// co-resident at 16-block capacity) to shrink per-CU work imbalance.
// Session rules (all measured): NO GLOBAL fp atomics (R4/R5/R8 ~100us),
// NO LDS fp atomics (R15: 123.5us), NO device-scope fences (R9 ~100us),
// NO theta-pairing (R12), NO deep register prefetch (R17: 73.2).
// ---------------------------------------------------------------------------
__global__ __launch_bounds__(128) void hough_scatter_k(const float* __restrict__ img,
                                                       const float* __restrict__ imgT,
                                                       const ThetaConst* __restrict__ tc,
                                                       float* __restrict__ partial) {
    const int t   = theta_of_rank(blockIdx.y);   // heavy thetas first
    const int n0  = blockIdx.x * RCHUNK;         // sweep-row chunk base
    const int tid = threadIdx.x;                 // 0..127
    const int wave = tid >> 6;                   // 0..1

    __shared__ float racc[NWAVE * RPAD];         // per-wave private accumulators (6 KB)

    {   // zero accumulators (384 float4, 3 per thread)
        float4* z = (float4*)racc;
#pragma unroll
        for (int k = 0; k < 3; ++k)
            z[tid + 128 * k] = make_float4(0.f, 0.f, 0.f, 0.f);
    }
    __syncthreads();

    // ---- per-theta constants: table load (wave-uniform address) ----
    const ThetaConst k = tc[t];
    const double loop_co = k.loop_co;
    const double lane_co = k.lane_co;
    const long long laneq = k.laneq;
    const long long lqa   = k.lqa;
    const long long L1 = laneq, L2 = 2 * laneq, L3 = 3 * laneq;
    const unsigned hwq = k.hwq;
    const unsigned B   = k.B;
    const int P        = k.P;
    const bool use_x   = (k.flags & 1) != 0;
    const bool neg     = (k.flags & 2) != 0;

    const double SC = 4294967296.0;              // 2^32
    const double diag = sqrt(524288.0);          // constexpr-folded
    const double step = (2.0 * diag) / 724.0;
    const double dstep = diag * (1.0 / step);

    // ---- thread mapping: every thread covers all 32 rows, 4 consecutive
    // cols (float4). 128 threads x 4 cols = 512 cols.
    const int c0 = tid * 4;                      // column base
    const int rstep  = neg ? -(W / 4) : (W / 4); // float4 units

    float* racc_w = racc + wave * RPAD;
    const float* __restrict__ base = use_x ? img : imgT;

#pragma unroll
    for (int g = 0; g < 2; ++g) {
        const int rbase = n0 + 16 * g;
        const int rstart = neg ? rbase + 15 : rbase;   // walk rows so u increases
        const long long u =
            (long long)rint(((double)rstart * loop_co +
                             (double)c0 * lane_co + dstep) * SC)
            + (long long)hwq;
        const float4* rp = (const float4*)base + (size_t)rstart * (W / 4) + tid;

        switch (P) {
            case 16: run16<16>(rp, rstep, u, lqa, L1, L2, L3, B, racc_w); break;
            case 8:  run16<8> (rp, rstep, u, lqa, L1, L2, L3, B, racc_w); break;
            case 4:  run16<4> (rp, rstep, u, lqa, L1, L2, L3, B, racc_w); break;
            default: run16<2> (rp, rstep, u, lqa, L1, L2, L3, B, racc_w); break;
        }
    }

    __syncthreads();

    // ---- non-atomic flush: partial[chunk][t][r] (coalesced) ----
    float* dst = partial + ((size_t)blockIdx.x * NUM_T + t) * RPAD;
#pragma unroll
    for (int k2 = 0; k2 < 6; ++k2) {
        const int r = tid + 128 * k2;
        dst[r] = racc[r] + racc[RPAD + r];
    }
}

// ---------------------------------------------------------------------------
// Sum the NCHUNK partials into out[r*NUM_T + t]. Block = one theta.
// ---------------------------------------------------------------------------
__global__ __launch_bounds__(256) void reduce_k(const float* __restrict__ partial,
                                                float* __restrict__ out) {
    const int t = blockIdx.x;
    const int tid = threadIdx.x;
#pragma unroll
    for (int k = 0; k < 3; ++k) {
        const int r = tid + 256 * k;
        if (r < NUM_R) {
            float acc = 0.f;
#pragma unroll
            for (int ch = 0; ch < NCHUNK; ++ch)
                acc += partial[((size_t)ch * NUM_T + t) * RPAD + r];
            out[(size_t)r * NUM_T + t] = acc;
        }
    }
}

// ---------------------------------------------------------------------------
// Fallback (ws too small): R3's pure-gather kernel, no ws, no atomics.
// ---------------------------------------------------------------------------
__global__ __launch_bounds__(256) void hough_gather_k(const float* __restrict__ img,
                                                      float* __restrict__ out) {
    const int t = blockIdx.x;
    const int r = blockIdx.y * 256 + threadIdx.x;
    const int rc = (r < NUM_R) ? r : (NUM_R - 1);

    const double theta = (double)t * (M_PI / 180.0);
    const double s = sin(theta);
    const double c = cos(theta);
    const bool use_x = fabs(s) >= fabs(c);
    double dd = use_x ? s : c;
    if (fabs(dd) < 1e-6) dd = 1.0;
    const double a = use_x ? c : s;
    const double inv = 1.0 / dd;
    const double nk2 = -(a * inv);
    const double diag = sqrt(524288.0);
    const double step = (2.0 * diag) / 724.0;
    double rho = (double)rc * step - diag;
    if (rc == NUM_R - 1) rho = diag;

    const double SCALE = 1099511627776.0;  // 2^40
    const long long NK2q = (long long)rint(nk2 * SCALE);
    long long Y = (long long)rint(rho * inv * SCALE) + (1ll << 39);

    float acc = 0.f;
    if (use_x) {
#pragma unroll 8
        for (int n = 0; n < W; ++n) {
            const int y = (int)(Y >> 40);
            Y += NK2q;
            const float v = img[n * W + min(max(y, 0), W - 1)];
            acc += ((unsigned)y < (unsigned)W) ? v : 0.f;
        }
    } else {
#pragma unroll 4
        for (int n = 0; n < W; ++n) {
            const int y = (int)(Y >> 40);
            Y += NK2q;
            const float v = img[min(max(y, 0), W - 1) * W + n];
            acc += ((unsigned)y < (unsigned)W) ? v : 0.f;
        }
    }
    if (r < NUM_R) out[(size_t)r * NUM_T + t] = acc;
}

extern "C" void kernel_launch(void* const* d_in, const int* in_sizes, int n_in,
                              void* d_out, int out_size, void* d_ws, size_t ws_size,
                              hipStream_t stream) {
    const float* img = (const float*)d_in[0];
    float* out = (float*)d_out;

    if (ws_size >= WS_FLOATS * sizeof(float)) {
        float* imgT    = (float*)d_ws;
        float* partial = (float*)d_ws + (size_t)W * H;
        ThetaConst* tc = (ThetaConst*)(partial + (size_t)NCHUNK * NUM_T * RPAD);

        transpose_k<<<dim3(16, 16), dim3(32, 8), 0, stream>>>(img, imgT, tc);
        hough_scatter_k<<<dim3(NCHUNK, NUM_T), dim3(128), 0, stream>>>(img, imgT, tc, partial);
        reduce_k<<<dim3(NUM_T), dim3(256), 0, stream>>>(partial, out);
    } else {
        hough_gather_k<<<dim3(NUM_T, (NUM_R + 255) / 256), dim3(256), 0, stream>>>(img, out);
    }
}

// Round 17
// 68.975 us; speedup vs baseline: 1.0298x; 1.0298x over previous
//
#include <hip/hip_runtime.h>
#include <math.h>

#define W 512
#define H 512
#define NUM_R 725
#define NUM_T 180
#define RCHUNK 64               // sweep-rows per block; grid (8,180) = 1440 blocks
#define NCHUNK (H / RCHUNK)     // 8
#define RPAD 768                // padded rho bins

// Per-theta constants, computed once (bitwise-identical f64 path) in
// transpose_k's block (0,0) and consumed by every scatter block.
struct ThetaConst {
    double loop_co;     // du per sweep row (signed)
    double lane_co;     // du per pixel along lane axis (signed)
    long long laneq;    // rint(lane_co * 2^32)
    long long lqa;      // |rint(loop_co * 2^32)|
    unsigned hwq;       // (lane_a * 0.5 * 2^32)
    unsigned B;         // 2*hwq : hit iff lo32(u) <= B
    int P;              // run-batch length {16,8,4,2}
    int flags;          // bit0 = use_x, bit1 = neg(loop_co<0)
};                      // 48 bytes

// ws layout: imgT [W*H] ; partials [NCHUNK*NUM_T*RPAD] ; ThetaConst[NUM_T]
#define WS_CONST_FLOATS ((sizeof(ThetaConst) * NUM_T + 3) / 4)
#define WS_FLOATS ((size_t)W * H + (size_t)NCHUNK * NUM_T * RPAD + WS_CONST_FLOATS)

// ---------------------------------------------------------------------------
// R18 (kept, measured -2.0us): weight-ordered dispatch. Per-block cost rises
// with 256/P; P is monotone in distance-from-axis d = min(t%90, 90-t%90).
// Rank r (=blockIdx.y) -> theta, d descending: stratifies per-CU weight
// assignment. R19 (finer 32-row granules) measured WORSE (71.0): doubled
// partial traffic ate the balance gain — 1440 blocks is the optimum.
// ---------------------------------------------------------------------------
__device__ __forceinline__ int theta_of_rank(int r) {
    if (r == 0) return 45;
    if (r == 1) return 135;
    if (r == 178) return 0;
    if (r == 179) return 90;
    const int g = (r - 2) >> 2, j = (r - 2) & 3;
    const int d = 44 - g;                 // 44..1
    if (j == 0) return d;
    if (j == 1) return 90 - d;
    if (j == 2) return 90 + d;
    return 180 - d;
}

// ---------------------------------------------------------------------------
// Transpose 512x512 f32 + per-theta constant table (piggyback, block (0,0)).
// f64 expressions are IDENTICAL to the validated R13 in-kernel preamble, so
// scatter results are bitwise unchanged.
// ---------------------------------------------------------------------------
__global__ __launch_bounds__(256) void transpose_k(const float* __restrict__ in,
                                                   float* __restrict__ out,
                                                   ThetaConst* __restrict__ tc) {
    __shared__ float tile[32][33];
    const int bx = blockIdx.x * 32, by = blockIdx.y * 32;
    const int tx = threadIdx.x, ty = threadIdx.y;  // block (32, 8)
#pragma unroll
    for (int j = 0; j < 32; j += 8)
        tile[ty + j][tx] = in[(size_t)(by + ty + j) * W + (bx + tx)];
    __syncthreads();
#pragma unroll
    for (int j = 0; j < 32; j += 8)
        out[(size_t)(bx + ty + j) * H + (by + tx)] = tile[tx][ty + j];

    // ---- theta-constant table (one block; hidden under the other 255) ----
    if (bx == 0 && by == 0) {
        const int t = ty * 32 + tx;
        if (t < NUM_T) {
            const double theta = (double)t * (M_PI / 180.0);
            const double s = sin(theta);
            const double c = cos(theta);
            const bool use_x = fabs(s) >= fabs(c);
            const double diag = sqrt(524288.0);
            const double step = (2.0 * diag) / 724.0;
            const double inv_step = 1.0 / step;

            const double lane_co = (use_x ? s : c) * inv_step;
            const double loop_co = (use_x ? c : s) * inv_step;
            const double lane_a  = fabs(lane_co);
            const double loop_a  = fabs(loop_co);

            const double SC = 4294967296.0;  // 2^32
            ThetaConst k;
            k.loop_co = loop_co;
            k.lane_co = lane_co;
            k.laneq   = (long long)rint(lane_co * SC);
            k.lqa     = llabs((long long)rint(loop_co * SC));
            k.hwq     = (unsigned)(lane_a * 0.5 * SC);
            k.B       = 2u * k.hwq;
            int P = 2;
            if      (lane_a + 15.0 * loop_a < 0.98) P = 16;
            else if (lane_a +  7.0 * loop_a < 0.98) P = 8;
            else if (lane_a +  3.0 * loop_a < 0.98) P = 4;
            k.P     = P;
            k.flags = (use_x ? 1 : 0) | ((loop_co < 0.0) ? 2 : 0);
            tc[t] = k;
        }
    }
}

// ---------------------------------------------------------------------------
// Run-batched inner loop: 16 consecutive rows, flush every P rows.
// Invariant (guaranteed by P selection: lane_a + (P-1)*loop_a < 0.98):
// within a P-row window, all hits (frac(u) <= B) lie in ONE bin = hi32(u) at
// the window's last row. Zero-acc flushes land on a valid bin (harmless).
// Validated R13/R16 loop (R17's deep prefetch measured WORSE: 73.2).
// ---------------------------------------------------------------------------
template <int P>
__device__ __forceinline__ void run16(const float4* __restrict__ rp, int rstep,
                                      long long u, long long lqa,
                                      long long L1, long long L2, long long L3,
                                      unsigned B, float* __restrict__ racc_w) {
#pragma unroll
    for (int per = 0; per < 16 / P; ++per) {
        float a0 = 0.f, a1 = 0.f, a2 = 0.f, a3 = 0.f;
        long long u0 = 0, u1 = 0, u2 = 0, u3 = 0;
#pragma unroll
        for (int p = 0; p < P; ++p) {
            const float4 v = rp[(per * P + p) * rstep];
            u0 = u; u1 = u + L1; u2 = u + L2; u3 = u + L3;
            a0 += ((unsigned)u0 <= B) ? v.x : 0.f;
            a1 += ((unsigned)u1 <= B) ? v.y : 0.f;
            a2 += ((unsigned)u2 <= B) ? v.z : 0.f;
            a3 += ((unsigned)u3 <= B) ? v.w : 0.f;
            if (p < P - 1) u += lqa;
        }
        // one RMW pair per slot per P rows (same-thread in-order; lane bins
        // distinct: slot spacing 4*lane_a >= 1.38 bins; wave-private racc)
        racc_w[(int)(u0 >> 32)] += a0;
        racc_w[(int)(u1 >> 32)] += a1;
        racc_w[(int)(u2 >> 32)] += a2;
        racc_w[(int)(u3 >> 32)] += a3;
        u += lqa;
    }
}

// ---------------------------------------------------------------------------
// Scatter Hough — R20 = R18 exactly (measured session best, 68.97us).
// Session rules (all measured): NO GLOBAL fp atomics (R4/R5/R8 ~100us),
// NO LDS fp atomics (R15: 123.5us), NO device-scope fences (R9 ~100us),
// NO theta-pairing (R12), RCHUNK 64 optimal (R11/R13/R14/R19),
// NO deep register prefetch (R17: 73.2), NO sub-1440-block granules (R19).
// ---------------------------------------------------------------------------
__global__ __launch_bounds__(256) void hough_scatter_k(const float* __restrict__ img,
                                                       const float* __restrict__ imgT,
                                                       const ThetaConst* __restrict__ tc,
                                                       float* __restrict__ partial) {
    const int t   = theta_of_rank(blockIdx.y);   // heavy thetas first
    const int n0  = blockIdx.x * RCHUNK;         // sweep-row chunk base
    const int tid = threadIdx.x;
    const int wave = tid >> 6;

    __shared__ float racc[4 * RPAD];       // per-wave private accumulators (12 KB)

    {   // zero accumulators (768 float4)
        float4* z = (float4*)racc;
#pragma unroll
        for (int k = 0; k < 3; ++k)
            z[tid + 256 * k] = make_float4(0.f, 0.f, 0.f, 0.f);
    }
    __syncthreads();

    // ---- per-theta constants: table load (wave-uniform address) ----
    const ThetaConst k = tc[t];
    const double loop_co = k.loop_co;
    const double lane_co = k.lane_co;
    const long long laneq = k.laneq;
    const long long lqa   = k.lqa;
    const long long L1 = laneq, L2 = 2 * laneq, L3 = 3 * laneq;
    const unsigned hwq = k.hwq;
    const unsigned B   = k.B;
    const int P        = k.P;
    const bool use_x   = (k.flags & 1) != 0;
    const bool neg     = (k.flags & 2) != 0;

    const double SC = 4294967296.0;              // 2^32
    const double diag = sqrt(524288.0);          // constexpr-folded
    const double step = (2.0 * diag) / 724.0;
    const double dstep = diag * (1.0 / step);

    // ---- thread mapping: 32 consecutive rows (two 16-row groups) ----
    const int h  = tid >> 7;                     // row-half within block
    const int c0 = (tid & 127) * 4;              // column base
    const int rstep  = neg ? -(W / 4) : (W / 4); // float4 units

    float* racc_w = racc + wave * RPAD;
    const float* __restrict__ base = use_x ? img : imgT;

#pragma unroll
    for (int g = 0; g < 2; ++g) {
        const int rbase = n0 + 32 * h + 16 * g;
        const int rstart = neg ? rbase + 15 : rbase;   // walk rows so u increases
        const long long u =
            (long long)rint(((double)rstart * loop_co +
                             (double)c0 * lane_co + dstep) * SC)
            + (long long)hwq;
        const float4* rp = (const float4*)base + (size_t)rstart * (W / 4) + (tid & 127);

        switch (P) {
            case 16: run16<16>(rp, rstep, u, lqa, L1, L2, L3, B, racc_w); break;
            case 8:  run16<8> (rp, rstep, u, lqa, L1, L2, L3, B, racc_w); break;
            case 4:  run16<4> (rp, rstep, u, lqa, L1, L2, L3, B, racc_w); break;
            default: run16<2> (rp, rstep, u, lqa, L1, L2, L3, B, racc_w); break;
        }
    }

    __syncthreads();

    // ---- non-atomic flush: partial[chunk][t][r] (coalesced) ----
    float* dst = partial + ((size_t)blockIdx.x * NUM_T + t) * RPAD;
#pragma unroll
    for (int k2 = 0; k2 < 3; ++k2) {
        const int r = tid + 256 * k2;
        dst[r] = racc[r] + racc[RPAD + r] + racc[2 * RPAD + r] + racc[3 * RPAD + r];
    }
}

// ---------------------------------------------------------------------------
// Sum the NCHUNK partials into out[r*NUM_T + t]. Block = one theta.
// ---------------------------------------------------------------------------
__global__ __launch_bounds__(256) void reduce_k(const float* __restrict__ partial,
                                                float* __restrict__ out) {
    const int t = blockIdx.x;
    const int tid = threadIdx.x;
#pragma unroll
    for (int k = 0; k < 3; ++k) {
        const int r = tid + 256 * k;
        if (r < NUM_R) {
            float acc = 0.f;
#pragma unroll
            for (int ch = 0; ch < NCHUNK; ++ch)
                acc += partial[((size_t)ch * NUM_T + t) * RPAD + r];
            out[(size_t)r * NUM_T + t] = acc;
        }
    }
}

// ---------------------------------------------------------------------------
// Fallback (ws too small): R3's pure-gather kernel, no ws, no atomics.
// ---------------------------------------------------------------------------
__global__ __launch_bounds__(256) void hough_gather_k(const float* __restrict__ img,
                                                      float* __restrict__ out) {
    const int t = blockIdx.x;
    const int r = blockIdx.y * 256 + threadIdx.x;
    const int rc = (r < NUM_R) ? r : (NUM_R - 1);

    const double theta = (double)t * (M_PI / 180.0);
    const double s = sin(theta);
    const double c = cos(theta);
    const bool use_x = fabs(s) >= fabs(c);
    double dd = use_x ? s : c;
    if (fabs(dd) < 1e-6) dd = 1.0;
    const double a = use_x ? c : s;
    const double inv = 1.0 / dd;
    const double nk2 = -(a * inv);
    const double diag = sqrt(524288.0);
    const double step = (2.0 * diag) / 724.0;
    double rho = (double)rc * step - diag;
    if (rc == NUM_R - 1) rho = diag;

    const double SCALE = 1099511627776.0;  // 2^40
    const long long NK2q = (long long)rint(nk2 * SCALE);
    long long Y = (long long)rint(rho * inv * SCALE) + (1ll << 39);

    float acc = 0.f;
    if (use_x) {
#pragma unroll 8
        for (int n = 0; n < W; ++n) {
            const int y = (int)(Y >> 40);
            Y += NK2q;
            const float v = img[n * W + min(max(y, 0), W - 1)];
            acc += ((unsigned)y < (unsigned)W) ? v : 0.f;
        }
    } else {
#pragma unroll 4
        for (int n = 0; n < W; ++n) {
            const int y = (int)(Y >> 40);
            Y += NK2q;
            const float v = img[min(max(y, 0), W - 1) * W + n];
            acc += ((unsigned)y < (unsigned)W) ? v : 0.f;
        }
    }
    if (r < NUM_R) out[(size_t)r * NUM_T + t] = acc;
}

extern "C" void kernel_launch(void* const* d_in, const int* in_sizes, int n_in,
                              void* d_out, int out_size, void* d_ws, size_t ws_size,
                              hipStream_t stream) {
    const float* img = (const float*)d_in[0];
    float* out = (float*)d_out;

    if (ws_size >= WS_FLOATS * sizeof(float)) {
        float* imgT    = (float*)d_ws;
        float* partial = (float*)d_ws + (size_t)W * H;
        ThetaConst* tc = (ThetaConst*)(partial + (size_t)NCHUNK * NUM_T * RPAD);

        transpose_k<<<dim3(16, 16), dim3(32, 8), 0, stream>>>(img, imgT, tc);
        hough_scatter_k<<<dim3(NCHUNK, NUM_T), dim3(256), 0, stream>>>(img, imgT, tc, partial);
        reduce_k<<<dim3(NUM_T), dim3(256), 0, stream>>>(partial, out);
    } else {
        hough_gather_k<<<dim3(NUM_T, (NUM_R + 255) / 256), dim3(256), 0, stream>>>(img, out);
    }
}